// Round 5
// baseline (560.655 us; speedup 1.0000x reference)
//
#include <hip/hip_runtime.h>
#include <math.h>

// B=64, M=128, J=512, T=513, E=256, H=16, D=16; out (64, 65664) fp32.

#define LDT 68    // 64-row A-tile LDS leading dim (fp32 gemms)
#define LDB 132   // 128-col B-tile LDS leading dim (fp32 gemms)

typedef __attribute__((ext_vector_type(8))) short bf16x8;   // 8 bf16 = 4 VGPR
typedef __attribute__((ext_vector_type(4))) float f32x4;    // MFMA acc

static __device__ inline unsigned short f2bf(float x) {     // RNE fp32->bf16
  unsigned u = __float_as_uint(x);
  return (unsigned short)((u + 0x7fffu + ((u >> 16) & 1u)) >> 16);
}
static __device__ inline float bf2f(unsigned short h) {
  return __uint_as_float(((unsigned)h) << 16);
}
static __device__ inline unsigned pk(unsigned short a, unsigned short b) {
  return (unsigned)a | ((unsigned)b << 16);
}

// ---------------------------------------------------------------------------
// One-time W split+transpose: Wt[col][k] (bf16 hi/lo), col 0..255 = Wk cols,
// 256..511 = Wv cols. grid 512 blocks x 256 thr (thread = k).
// ---------------------------------------------------------------------------
__global__ void prep_wt(const float* __restrict__ Wk, const float* __restrict__ Wv,
                        unsigned short* __restrict__ Wth, unsigned short* __restrict__ Wtl)
{
  const int c = blockIdx.x, k = threadIdx.x;
  const float x = (c < 256) ? Wk[k * 256 + c] : Wv[k * 256 + (c - 256)];
  const unsigned short h = f2bf(x);
  Wth[c * 256 + k] = h;
  Wtl[c * 256 + k] = f2bf(x - bf2f(h));
}

// ---------------------------------------------------------------------------
// Split-bf16 MFMA GEMM: C(32832 x 512) = vjobs(32832 x 256) @ [Wk|Wv].
// 128x128 tile, 256 thr = 4 waves (2x2, each 64x64 via 4x4 16x16x32 tiles).
// C = Ah*Bh + Ah*Bl + Al*Bh  (error ~2^-17, fp32-grade for this use).
// ---------------------------------------------------------------------------
__global__ __launch_bounds__(256) void gemm_kv_mfma(
    const float* __restrict__ jobs, const float* __restrict__ skip,
    const unsigned short* __restrict__ Wth, const unsigned short* __restrict__ Wtl,
    float* __restrict__ Kw, float* __restrict__ Vw)
{
  __shared__ short Ah[128 * 32], Al[128 * 32];   // [row][k] bf16, 8KB each
  __shared__ short Bh[128 * 32], Bl[128 * 32];   // [col][k] bf16
  const int tid = threadIdx.x;
  const int bx = blockIdx.x, by = blockIdx.y;

  const int r16 = tid >> 1;
  const int h16 = (tid & 1) << 4;
  int rg = by * 128 + r16; if (rg > 32831) rg = 32831;
  const int bb = rg / 513, tt = rg - bb * 513;
  const float* arow = (tt == 0) ? skip : (jobs + ((size_t)(bb * 512 + tt - 1) << 8));
  const unsigned short* bhrow = Wth + ((size_t)(bx * 128 + r16) << 8);
  const unsigned short* blrow = Wtl + ((size_t)(bx * 128 + r16) << 8);

  const int w = tid >> 6, lane = tid & 63;
  const int wr = (w >> 1) << 6, wc = (w & 1) << 6;
  const int fm = lane & 15, fq = lane >> 4;

  f32x4 acc[4][4] = {};

  for (int kk = 0; kk < 256; kk += 32) {
    const float4 a0 = *(const float4*)(arow + kk + h16);
    const float4 a1 = *(const float4*)(arow + kk + h16 + 4);
    const float4 a2 = *(const float4*)(arow + kk + h16 + 8);
    const float4 a3 = *(const float4*)(arow + kk + h16 + 12);
    const int4 bh0 = *(const int4*)(bhrow + kk + h16);
    const int4 bh1 = *(const int4*)(bhrow + kk + h16 + 8);
    const int4 bl0 = *(const int4*)(blrow + kk + h16);
    const int4 bl1 = *(const int4*)(blrow + kk + h16 + 8);

    unsigned short h[16], l[16];
    const float av[16] = {a0.x,a0.y,a0.z,a0.w, a1.x,a1.y,a1.z,a1.w,
                          a2.x,a2.y,a2.z,a2.w, a3.x,a3.y,a3.z,a3.w};
    #pragma unroll
    for (int i = 0; i < 16; ++i) {
      h[i] = f2bf(av[i]);
      l[i] = f2bf(av[i] - bf2f(h[i]));
    }

    __syncthreads();
    const int so = r16 * 32 + h16;
    ((int4*)&Ah[so])[0] = make_int4(pk(h[0],h[1]), pk(h[2],h[3]), pk(h[4],h[5]), pk(h[6],h[7]));
    ((int4*)&Ah[so])[1] = make_int4(pk(h[8],h[9]), pk(h[10],h[11]), pk(h[12],h[13]), pk(h[14],h[15]));
    ((int4*)&Al[so])[0] = make_int4(pk(l[0],l[1]), pk(l[2],l[3]), pk(l[4],l[5]), pk(l[6],l[7]));
    ((int4*)&Al[so])[1] = make_int4(pk(l[8],l[9]), pk(l[10],l[11]), pk(l[12],l[13]), pk(l[14],l[15]));
    *(int4*)&Bh[so] = bh0; *(int4*)&Bh[so + 8] = bh1;
    *(int4*)&Bl[so] = bl0; *(int4*)&Bl[so + 8] = bl1;
    __syncthreads();

    bf16x8 afh[4], afl[4], bfh[4], bfl[4];
    #pragma unroll
    for (int i = 0; i < 4; ++i) {
      const int ai = (wr + i * 16 + fm) * 32 + fq * 8;
      const int bi = (wc + i * 16 + fm) * 32 + fq * 8;
      afh[i] = *(const bf16x8*)&Ah[ai];
      afl[i] = *(const bf16x8*)&Al[ai];
      bfh[i] = *(const bf16x8*)&Bh[bi];
      bfl[i] = *(const bf16x8*)&Bl[bi];
    }
    #pragma unroll
    for (int mi = 0; mi < 4; ++mi)
      #pragma unroll
      for (int ni = 0; ni < 4; ++ni) {
        acc[mi][ni] = __builtin_amdgcn_mfma_f32_16x16x32_bf16(afh[mi], bfl[ni], acc[mi][ni], 0, 0, 0);
        acc[mi][ni] = __builtin_amdgcn_mfma_f32_16x16x32_bf16(afl[mi], bfh[ni], acc[mi][ni], 0, 0, 0);
        acc[mi][ni] = __builtin_amdgcn_mfma_f32_16x16x32_bf16(afh[mi], bfh[ni], acc[mi][ni], 0, 0, 0);
      }
  }

  float* Cb = (bx < 2) ? Kw : Vw;
  const int cb = ((bx & 1) << 7) + wc;
  #pragma unroll
  for (int mi = 0; mi < 4; ++mi) {
    #pragma unroll
    for (int r = 0; r < 4; ++r) {
      const int row = by * 128 + wr + mi * 16 + fq * 4 + r;
      if (row < 32832) {
        float* crow = Cb + (size_t)row * 256 + cb;
        #pragma unroll
        for (int ni = 0; ni < 4; ++ni)
          crow[ni * 16 + fm] = acc[mi][ni][r];
      }
    }
  }
}

// ---------------------------------------------------------------------------
// Wide tiled fp32 GEMM (Q and Wc projections): C[rows x 256] = A @ W (+bias)
// ---------------------------------------------------------------------------
template<int MODE>
__global__ __launch_bounds__(256) void gemm_wide(
    const float* __restrict__ A, const float* __restrict__ jobs,
    const float* __restrict__ skip, const float* __restrict__ W1,
    const float* __restrict__ bias, float* __restrict__ C1)
{
  __shared__ float As[16 * LDT];
  __shared__ float Bs[16 * LDB];
  const int tid = threadIdx.x;
  const int bx = blockIdx.x, by = blockIdx.y;

  const float* W = W1; float* C = C1; const int col0 = bx * 128;

  const int a_row = tid >> 2;
  const int a_k4  = (tid & 3) << 2;
  const int row = by * 64 + a_row;
  const float* arow;
  if (MODE == 0) {
    arow = A + ((size_t)row << 8);
  } else {
    const int bb = row / 513;
    const int t  = row - bb * 513;
    arow = (t == 0) ? skip : (jobs + ((size_t)(bb * 512 + t - 1) << 8));
  }

  const int b_k  = tid >> 4;
  const int b_c8 = (tid & 15) << 3;

  const int tr = tid >> 4, tc = tid & 15;
  float acc[4][8] = {};

  for (int k0 = 0; k0 < 256; k0 += 16) {
    const float4 av  = *(const float4*)(arow + k0 + a_k4);
    const float4 bv0 = *(const float4*)(W + ((size_t)(k0 + b_k) << 8) + col0 + b_c8);
    const float4 bv1 = *(const float4*)(W + ((size_t)(k0 + b_k) << 8) + col0 + b_c8 + 4);
    __syncthreads();
    As[(a_k4 + 0) * LDT + a_row] = av.x;
    As[(a_k4 + 1) * LDT + a_row] = av.y;
    As[(a_k4 + 2) * LDT + a_row] = av.z;
    As[(a_k4 + 3) * LDT + a_row] = av.w;
    *(float4*)&Bs[b_k * LDB + b_c8]     = bv0;
    *(float4*)&Bs[b_k * LDB + b_c8 + 4] = bv1;
    __syncthreads();
    #pragma unroll
    for (int k = 0; k < 16; ++k) {
      const float4 a  = *(const float4*)&As[k * LDT + (tr << 2)];
      const float4 b0 = *(const float4*)&Bs[k * LDB + (tc << 3)];
      const float4 b1 = *(const float4*)&Bs[k * LDB + (tc << 3) + 4];
      const float aa[4] = {a.x, a.y, a.z, a.w};
      #pragma unroll
      for (int i = 0; i < 4; ++i) {
        acc[i][0] = fmaf(aa[i], b0.x, acc[i][0]);
        acc[i][1] = fmaf(aa[i], b0.y, acc[i][1]);
        acc[i][2] = fmaf(aa[i], b0.z, acc[i][2]);
        acc[i][3] = fmaf(aa[i], b0.w, acc[i][3]);
        acc[i][4] = fmaf(aa[i], b1.x, acc[i][4]);
        acc[i][5] = fmaf(aa[i], b1.y, acc[i][5]);
        acc[i][6] = fmaf(aa[i], b1.z, acc[i][6]);
        acc[i][7] = fmaf(aa[i], b1.w, acc[i][7]);
      }
    }
  }

  const int oc = col0 + (tc << 3);
  float4 bsa = make_float4(0.f,0.f,0.f,0.f), bsb = make_float4(0.f,0.f,0.f,0.f);
  if (bias) { bsa = *(const float4*)(bias + oc); bsb = *(const float4*)(bias + oc + 4); }
  #pragma unroll
  for (int i = 0; i < 4; ++i) {
    float* crow = C + ((size_t)(by * 64 + (tr << 2) + i) << 8) + oc;
    float4 o0, o1;
    o0.x = acc[i][0]+bsa.x; o0.y = acc[i][1]+bsa.y; o0.z = acc[i][2]+bsa.z; o0.w = acc[i][3]+bsa.w;
    o1.x = acc[i][4]+bsb.x; o1.y = acc[i][5]+bsb.y; o1.z = acc[i][6]+bsb.z; o1.w = acc[i][7]+bsb.w;
    *(float4*)crow = o0; *(float4*)(crow + 4) = o1;
  }
}

// ---------------------------------------------------------------------------
// Attention partials v2: grid (h=16, b=64, c=2), block 256 = 2 t-halves x 128 m.
// Unroll-2 over t (16 loads in flight); q pre-scaled by 0.25; halves combined
// in LDS, written in the same (c=2) Opart/Lpart layout as before.
// ---------------------------------------------------------------------------
__global__ __launch_bounds__(256) void attn_part(
    const float* __restrict__ Q, const float* __restrict__ K,
    const float* __restrict__ V, float* __restrict__ Opart,
    float* __restrict__ Lpart)
{
  const int h = blockIdx.x, b = blockIdx.y, c = blockIdx.z;
  const int tid = threadIdx.x;
  const int m = tid & 127, half = tid >> 7;
  // chunk c: [cs,ce); this half: [ts,te)
  const int cs  = c ? 257 : 0;
  const int mid = c ? 385 : 129;
  const int ce  = c ? 513 : 257;
  const int ts  = half ? mid : cs;
  const int te  = half ? ce : mid;

  __shared__ float Os[128 * 17];

  float q[16];
  {
    const float* qp = Q + ((size_t)(b * 128 + m) << 8) + h * 16;
    #pragma unroll
    for (int i = 0; i < 16; i += 4) {
      const float4 v = *(const float4*)(qp + i);
      q[i] = v.x * 0.25f; q[i+1] = v.y * 0.25f;
      q[i+2] = v.z * 0.25f; q[i+3] = v.w * 0.25f;
    }
  }

  float l = 0.f, o[16] = {};
  const float* kp = K + ((size_t)(b * 513 + ts) << 8) + h * 16;
  const float* vp = V + ((size_t)(b * 513 + ts) << 8) + h * 16;

  int t = ts;
  for (; t + 1 < te; t += 2) {
    // 16 independent loads (2 K rows + 2 V rows)
    const float4 ka0 = *(const float4*)(kp);
    const float4 ka1 = *(const float4*)(kp + 4);
    const float4 ka2 = *(const float4*)(kp + 8);
    const float4 ka3 = *(const float4*)(kp + 12);
    const float4 kb0 = *(const float4*)(kp + 256);
    const float4 kb1 = *(const float4*)(kp + 260);
    const float4 kb2 = *(const float4*)(kp + 264);
    const float4 kb3 = *(const float4*)(kp + 268);
    const float4 va0 = *(const float4*)(vp);
    const float4 va1 = *(const float4*)(vp + 4);
    const float4 va2 = *(const float4*)(vp + 8);
    const float4 va3 = *(const float4*)(vp + 12);
    const float4 vb0 = *(const float4*)(vp + 256);
    const float4 vb1 = *(const float4*)(vp + 260);
    const float4 vb2 = *(const float4*)(vp + 264);
    const float4 vb3 = *(const float4*)(vp + 268);

    float s0 = q[0]*ka0.x;  s0 = fmaf(q[1],ka0.y,s0);  s0 = fmaf(q[2],ka0.z,s0);  s0 = fmaf(q[3],ka0.w,s0);
    float s1 = q[4]*ka1.x;  s1 = fmaf(q[5],ka1.y,s1);  s1 = fmaf(q[6],ka1.z,s1);  s1 = fmaf(q[7],ka1.w,s1);
    float s2 = q[8]*ka2.x;  s2 = fmaf(q[9],ka2.y,s2);  s2 = fmaf(q[10],ka2.z,s2); s2 = fmaf(q[11],ka2.w,s2);
    float s3 = q[12]*ka3.x; s3 = fmaf(q[13],ka3.y,s3); s3 = fmaf(q[14],ka3.z,s3); s3 = fmaf(q[15],ka3.w,s3);
    float u0 = q[0]*kb0.x;  u0 = fmaf(q[1],kb0.y,u0);  u0 = fmaf(q[2],kb0.z,u0);  u0 = fmaf(q[3],kb0.w,u0);
    float u1 = q[4]*kb1.x;  u1 = fmaf(q[5],kb1.y,u1);  u1 = fmaf(q[6],kb1.z,u1);  u1 = fmaf(q[7],kb1.w,u1);
    float u2 = q[8]*kb2.x;  u2 = fmaf(q[9],kb2.y,u2);  u2 = fmaf(q[10],kb2.z,u2); u2 = fmaf(q[11],kb2.w,u2);
    float u3 = q[12]*kb3.x; u3 = fmaf(q[13],kb3.y,u3); u3 = fmaf(q[14],kb3.z,u3); u3 = fmaf(q[15],kb3.w,u3);
    const float ea = __expf((s0 + s1) + (s2 + s3));
    const float eb = __expf((u0 + u1) + (u2 + u3));
    l += ea + eb;
    o[0]  = fmaf(ea, va0.x, o[0]);  o[0]  = fmaf(eb, vb0.x, o[0]);
    o[1]  = fmaf(ea, va0.y, o[1]);  o[1]  = fmaf(eb, vb0.y, o[1]);
    o[2]  = fmaf(ea, va0.z, o[2]);  o[2]  = fmaf(eb, vb0.z, o[2]);
    o[3]  = fmaf(ea, va0.w, o[3]);  o[3]  = fmaf(eb, vb0.w, o[3]);
    o[4]  = fmaf(ea, va1.x, o[4]);  o[4]  = fmaf(eb, vb1.x, o[4]);
    o[5]  = fmaf(ea, va1.y, o[5]);  o[5]  = fmaf(eb, vb1.y, o[5]);
    o[6]  = fmaf(ea, va1.z, o[6]);  o[6]  = fmaf(eb, vb1.z, o[6]);
    o[7]  = fmaf(ea, va1.w, o[7]);  o[7]  = fmaf(eb, vb1.w, o[7]);
    o[8]  = fmaf(ea, va2.x, o[8]);  o[8]  = fmaf(eb, vb2.x, o[8]);
    o[9]  = fmaf(ea, va2.y, o[9]);  o[9]  = fmaf(eb, vb2.y, o[9]);
    o[10] = fmaf(ea, va2.z, o[10]); o[10] = fmaf(eb, vb2.z, o[10]);
    o[11] = fmaf(ea, va2.w, o[11]); o[11] = fmaf(eb, vb2.w, o[11]);
    o[12] = fmaf(ea, va3.x, o[12]); o[12] = fmaf(eb, vb3.x, o[12]);
    o[13] = fmaf(ea, va3.y, o[13]); o[13] = fmaf(eb, vb3.y, o[13]);
    o[14] = fmaf(ea, va3.z, o[14]); o[14] = fmaf(eb, vb3.z, o[14]);
    o[15] = fmaf(ea, va3.w, o[15]); o[15] = fmaf(eb, vb3.w, o[15]);
    kp += 512; vp += 512;
  }
  if (t < te) {   // odd tail (only the c=0 low half hits this)
    const float4 k0 = *(const float4*)(kp);
    const float4 k1 = *(const float4*)(kp + 4);
    const float4 k2 = *(const float4*)(kp + 8);
    const float4 k3 = *(const float4*)(kp + 12);
    const float4 v0 = *(const float4*)(vp);
    const float4 v1 = *(const float4*)(vp + 4);
    const float4 v2 = *(const float4*)(vp + 8);
    const float4 v3 = *(const float4*)(vp + 12);
    float s0 = q[0]*k0.x;  s0 = fmaf(q[1],k0.y,s0);  s0 = fmaf(q[2],k0.z,s0);  s0 = fmaf(q[3],k0.w,s0);
    float s1 = q[4]*k1.x;  s1 = fmaf(q[5],k1.y,s1);  s1 = fmaf(q[6],k1.z,s1);  s1 = fmaf(q[7],k1.w,s1);
    float s2 = q[8]*k2.x;  s2 = fmaf(q[9],k2.y,s2);  s2 = fmaf(q[10],k2.z,s2); s2 = fmaf(q[11],k2.w,s2);
    float s3 = q[12]*k3.x; s3 = fmaf(q[13],k3.y,s3); s3 = fmaf(q[14],k3.z,s3); s3 = fmaf(q[15],k3.w,s3);
    const float e = __expf((s0 + s1) + (s2 + s3));
    l += e;
    o[0]  = fmaf(e, v0.x, o[0]);  o[1]  = fmaf(e, v0.y, o[1]);
    o[2]  = fmaf(e, v0.z, o[2]);  o[3]  = fmaf(e, v0.w, o[3]);
    o[4]  = fmaf(e, v1.x, o[4]);  o[5]  = fmaf(e, v1.y, o[5]);
    o[6]  = fmaf(e, v1.z, o[6]);  o[7]  = fmaf(e, v1.w, o[7]);
    o[8]  = fmaf(e, v2.x, o[8]);  o[9]  = fmaf(e, v2.y, o[9]);
    o[10] = fmaf(e, v2.z, o[10]); o[11] = fmaf(e, v2.w, o[11]);
    o[12] = fmaf(e, v3.x, o[12]); o[13] = fmaf(e, v3.y, o[13]);
    o[14] = fmaf(e, v3.z, o[14]); o[15] = fmaf(e, v3.w, o[15]);
  }

  // combine halves via LDS (stride 17: conflict-free scalar access)
  if (half) {
    #pragma unroll
    for (int i = 0; i < 16; ++i) Os[m * 17 + i] = o[i];
    Os[m * 17 + 16] = l;
  }
  __syncthreads();
  if (!half) {
    #pragma unroll
    for (int i = 0; i < 16; ++i) o[i] += Os[m * 17 + i];
    l += Os[m * 17 + 16];
    const int idx = (b * 16 + h) * 128 + m;
    float* op = Opart + ((size_t)(c * 131072 + idx) << 4);
    #pragma unroll
    for (int i = 0; i < 16; i += 4) {
      float4 v; v.x = o[i]; v.y = o[i+1]; v.z = o[i+2]; v.w = o[i+3];
      *(float4*)(op + i) = v;
    }
    Lpart[c * 131072 + idx] = l;
  }
}

// Combine 2 T-chunks: o = (o0+o1)/(l0+l1), write out_concat (B,M,H*D).
__global__ __launch_bounds__(256) void attn_combine(
    const float* __restrict__ Opart, const float* __restrict__ Lpart,
    float* __restrict__ OC)
{
  const int gid = blockIdx.x * 256 + threadIdx.x;   // < 131072
  const float* p0 = Opart + ((size_t)gid << 4);
  const float* p1 = Opart + ((size_t)(131072 + gid) << 4);
  const float inv = 1.f / (Lpart[gid] + Lpart[131072 + gid]);
  const int m = gid & 127, bh = gid >> 7, h = bh & 15, b = bh >> 4;
  float* op = OC + ((size_t)(b * 128 + m) << 8) + h * 16;
  #pragma unroll
  for (int i = 0; i < 16; i += 4) {
    const float4 a = *(const float4*)(p0 + i);
    const float4 c = *(const float4*)(p1 + i);
    float4 v;
    v.x = (a.x + c.x) * inv; v.y = (a.y + c.y) * inv;
    v.z = (a.z + c.z) * inv; v.w = (a.w + c.w) * inv;
    *(float4*)(op + i) = v;
  }
}

// ---------------------------------------------------------------------------
// Logits GEMM, fused exp(10*tanh(x/16)+mask-10) + deterministic partials.
// ---------------------------------------------------------------------------
__global__ __launch_bounds__(256) void logits_gemm(
    const float* __restrict__ MH, const float* __restrict__ jobs,
    const float* __restrict__ skip, const float* __restrict__ mask,
    float* __restrict__ out, float* __restrict__ partials)
{
  __shared__ float As[16 * LDT];
  __shared__ float Bs[16 * LDT];
  __shared__ float red[4];
  const int tid = threadIdx.x;
  const int b = blockIdx.z;

  const int m_l = tid >> 2;
  const int kk4 = (tid & 3) << 2;
  const float* arow = MH + ((size_t)(b * 128 + blockIdx.y * 64 + m_l) << 8);

  const int t_g = blockIdx.x * 64 + m_l;
  const float* brow = nullptr;
  if (t_g < 513)
    brow = (t_g == 0) ? skip : (jobs + ((size_t)(b * 512 + t_g - 1) << 8));

  const int tr = tid >> 4, tc = tid & 15;
  float acc[4][4] = {};

  for (int k0 = 0; k0 < 256; k0 += 16) {
    const float4 av = *(const float4*)(arow + k0 + kk4);
    float4 bv = make_float4(0.f, 0.f, 0.f, 0.f);
    if (brow) bv = *(const float4*)(brow + k0 + kk4);
    __syncthreads();
    As[(kk4 + 0) * LDT + m_l] = av.x;
    As[(kk4 + 1) * LDT + m_l] = av.y;
    As[(kk4 + 2) * LDT + m_l] = av.z;
    As[(kk4 + 3) * LDT + m_l] = av.w;
    Bs[(kk4 + 0) * LDT + m_l] = bv.x;
    Bs[(kk4 + 1) * LDT + m_l] = bv.y;
    Bs[(kk4 + 2) * LDT + m_l] = bv.z;
    Bs[(kk4 + 3) * LDT + m_l] = bv.w;
    __syncthreads();
    #pragma unroll
    for (int k = 0; k < 16; ++k) {
      const float4 a  = *(const float4*)&As[k * LDT + (tr << 2)];
      const float4 b4 = *(const float4*)&Bs[k * LDT + (tc << 2)];
      const float aa[4] = {a.x, a.y, a.z, a.w};
      #pragma unroll
      for (int i = 0; i < 4; ++i) {
        acc[i][0] = fmaf(aa[i], b4.x, acc[i][0]);
        acc[i][1] = fmaf(aa[i], b4.y, acc[i][1]);
        acc[i][2] = fmaf(aa[i], b4.z, acc[i][2]);
        acc[i][3] = fmaf(aa[i], b4.w, acc[i][3]);
      }
    }
  }

  float lsum = 0.f;
  #pragma unroll
  for (int i = 0; i < 4; ++i) {
    const int mm = blockIdx.y * 64 + (tr << 2) + i;
    #pragma unroll
    for (int j = 0; j < 4; ++j) {
      const int tt = blockIdx.x * 64 + (tc << 2) + j;
      if (tt < 513) {
        const float lg = 10.f * tanhf(acc[i][j] * 0.0625f)
                       + mask[((size_t)(b * 128 + mm)) * 513 + tt];
        const float e = __expf(lg - 10.f);
        out[(size_t)b * 65664 + (size_t)mm * 513 + tt] = e;
        lsum += e;
      }
    }
  }
  #pragma unroll
  for (int off = 32; off; off >>= 1) lsum += __shfl_xor(lsum, off);
  if ((tid & 63) == 0) red[tid >> 6] = lsum;
  __syncthreads();
  if (tid == 0)
    partials[b * 18 + blockIdx.x * 2 + blockIdx.y] =
        (red[0] + red[1]) + (red[2] + red[3]);
}

__global__ void sm_inv(const float* __restrict__ partials, float* __restrict__ invb)
{
  const int b = threadIdx.x;
  if (b < 64) {
    float s = 0.f;
    #pragma unroll
    for (int i = 0; i < 18; ++i) s += partials[b * 18 + i];
    invb[b] = 1.f / s;
  }
}

__global__ __launch_bounds__(256) void sm_norm(float* __restrict__ out,
                                               const float* __restrict__ invb)
{
  const int i4 = blockIdx.x * 256 + threadIdx.x;
  if (i4 < 1050624) {
    const int b = i4 / 16416;
    float4 v = ((float4*)out)[i4];
    const float s = invb[b];
    v.x *= s; v.y *= s; v.z *= s; v.w *= s;
    ((float4*)out)[i4] = v;
  }
}

// ---------------------------------------------------------------------------
extern "C" void kernel_launch(void* const* d_in, const int* in_sizes, int n_in,
                              void* d_out, int out_size, void* d_ws, size_t ws_size,
                              hipStream_t stream)
{
  const float* machine = (const float*)d_in[0];
  const float* jobs    = (const float*)d_in[1];
  const float* mask    = (const float*)d_in[2];
  const float* Wq      = (const float*)d_in[3];
  const float* Wk      = (const float*)d_in[4];
  const float* Wv      = (const float*)d_in[5];
  const float* Wc      = (const float*)d_in[6];
  const float* bc      = (const float*)d_in[7];
  const float* skip    = (const float*)d_in[8];

  // Workspace (floats). Peak 23,101,440 f = 92.4 MB (same as r1/r3/r4).
  float* ws       = (float*)d_ws;
  float* Qw       = ws;
  float* Kw       = ws + 2097152;
  float* Vw       = ws + 10502144;
  unsigned short* Wth = (unsigned short*)(ws + 18907136);  // dead before Opart written
  unsigned short* Wtl = Wth + 131072;
  float* Opart    = ws + 18907136;
  float* MH       = ws + 18907136;     // overlays Opart chunk0 (dead by then)
  float* partials = ws + 2097152;      // overlays Kw (dead after attn_part)
  float* invb     = partials + 1152;
  float* OC       = Qw;
  float* out      = (float*)d_out;
  float* Lpart    = out;               // dead before logits writes

  // Q = machine @ Wq3 (fp32)
  gemm_wide<0><<<dim3(2, 128), 256, 0, stream>>>(
      machine, nullptr, nullptr, Wq, nullptr, Qw);
  // W split/transpose, then K|V = vjobs @ [Wk|Wv] via split-bf16 MFMA
  prep_wt<<<512, 256, 0, stream>>>(Wk, Wv, Wth, Wtl);
  gemm_kv_mfma<<<dim3(4, 257), 256, 0, stream>>>(jobs, skip, Wth, Wtl, Kw, Vw);
  // attention partials + combine
  attn_part<<<dim3(16, 64, 2), 256, 0, stream>>>(Qw, Kw, Vw, Opart, Lpart);
  attn_combine<<<512, 256, 0, stream>>>(Opart, Lpart, OC);
  // mh = out_concat @ Wc + bc (fp32)
  gemm_wide<0><<<dim3(2, 128), 256, 0, stream>>>(
      OC, nullptr, nullptr, Wc, bc, MH);
  // exp(logits-10) + partials
  logits_gemm<<<dim3(9, 2, 64), 256, 0, stream>>>(MH, jobs, skip, mask, out, partials);
  sm_inv<<<1, 64, 0, stream>>>(partials, invb);
  sm_norm<<<4104, 256, 0, stream>>>(out, invb);
}

// Round 6
// 381.393 us; speedup vs baseline: 1.4700x; 1.4700x over previous
//
#include <hip/hip_runtime.h>
#include <math.h>

// B=64, M=128, J=512, T=513, E=256, H=16, D=16; out (64, 65664) fp32.

#define LDT 68    // 64-row A-tile LDS leading dim (fp32 gemms)
#define LDB 132   // 128-col B-tile LDS leading dim (fp32 gemms)

typedef __attribute__((ext_vector_type(8))) short bf16x8;   // 8 bf16 = 4 VGPR
typedef __attribute__((ext_vector_type(4))) float f32x4;    // MFMA acc

static __device__ inline unsigned short f2bf(float x) {     // RNE fp32->bf16
  unsigned u = __float_as_uint(x);
  return (unsigned short)((u + 0x7fffu + ((u >> 16) & 1u)) >> 16);
}
static __device__ inline float bf2f(unsigned short h) {
  return __uint_as_float(((unsigned)h) << 16);
}
static __device__ inline unsigned pk(unsigned short a, unsigned short b) {
  return (unsigned)a | ((unsigned)b << 16);
}

// ---------------------------------------------------------------------------
// One-time W split+transpose: Wt[col][k] (bf16 hi/lo), col 0..255 = Wk cols,
// 256..511 = Wv cols. grid 512 blocks x 256 thr (thread = k).
// ---------------------------------------------------------------------------
__global__ void prep_wt(const float* __restrict__ Wk, const float* __restrict__ Wv,
                        unsigned short* __restrict__ Wth, unsigned short* __restrict__ Wtl)
{
  const int c = blockIdx.x, k = threadIdx.x;
  const float x = (c < 256) ? Wk[k * 256 + c] : Wv[k * 256 + (c - 256)];
  const unsigned short h = f2bf(x);
  Wth[c * 256 + k] = h;
  Wtl[c * 256 + k] = f2bf(x - bf2f(h));
}

// ---------------------------------------------------------------------------
// Split-bf16 MFMA GEMM: C(32832 x 512) = vjobs(32832 x 256) @ [Wk|Wv].
// 128x128 tile, 256 thr = 4 waves (2x2, each 64x64 via 4x4 16x16x32 tiles).
// C = Ah*Bh + Ah*Bl + Al*Bh  (error ~2^-17, fp32-grade for this use).
// ---------------------------------------------------------------------------
__global__ __launch_bounds__(256) void gemm_kv_mfma(
    const float* __restrict__ jobs, const float* __restrict__ skip,
    const unsigned short* __restrict__ Wth, const unsigned short* __restrict__ Wtl,
    float* __restrict__ Kw, float* __restrict__ Vw)
{
  __shared__ short Ah[128 * 32], Al[128 * 32];   // [row][k] bf16, 8KB each
  __shared__ short Bh[128 * 32], Bl[128 * 32];   // [col][k] bf16
  const int tid = threadIdx.x;
  const int bx = blockIdx.x, by = blockIdx.y;

  const int r16 = tid >> 1;
  const int h16 = (tid & 1) << 4;
  int rg = by * 128 + r16; if (rg > 32831) rg = 32831;
  const int bb = rg / 513, tt = rg - bb * 513;
  const float* arow = (tt == 0) ? skip : (jobs + ((size_t)(bb * 512 + tt - 1) << 8));
  const unsigned short* bhrow = Wth + ((size_t)(bx * 128 + r16) << 8);
  const unsigned short* blrow = Wtl + ((size_t)(bx * 128 + r16) << 8);

  const int w = tid >> 6, lane = tid & 63;
  const int wr = (w >> 1) << 6, wc = (w & 1) << 6;
  const int fm = lane & 15, fq = lane >> 4;

  f32x4 acc[4][4] = {};

  for (int kk = 0; kk < 256; kk += 32) {
    const float4 a0 = *(const float4*)(arow + kk + h16);
    const float4 a1 = *(const float4*)(arow + kk + h16 + 4);
    const float4 a2 = *(const float4*)(arow + kk + h16 + 8);
    const float4 a3 = *(const float4*)(arow + kk + h16 + 12);
    const int4 bh0 = *(const int4*)(bhrow + kk + h16);
    const int4 bh1 = *(const int4*)(bhrow + kk + h16 + 8);
    const int4 bl0 = *(const int4*)(blrow + kk + h16);
    const int4 bl1 = *(const int4*)(blrow + kk + h16 + 8);

    unsigned short h[16], l[16];
    const float av[16] = {a0.x,a0.y,a0.z,a0.w, a1.x,a1.y,a1.z,a1.w,
                          a2.x,a2.y,a2.z,a2.w, a3.x,a3.y,a3.z,a3.w};
    #pragma unroll
    for (int i = 0; i < 16; ++i) {
      h[i] = f2bf(av[i]);
      l[i] = f2bf(av[i] - bf2f(h[i]));
    }

    __syncthreads();
    const int so = r16 * 32 + h16;
    ((int4*)&Ah[so])[0] = make_int4(pk(h[0],h[1]), pk(h[2],h[3]), pk(h[4],h[5]), pk(h[6],h[7]));
    ((int4*)&Ah[so])[1] = make_int4(pk(h[8],h[9]), pk(h[10],h[11]), pk(h[12],h[13]), pk(h[14],h[15]));
    ((int4*)&Al[so])[0] = make_int4(pk(l[0],l[1]), pk(l[2],l[3]), pk(l[4],l[5]), pk(l[6],l[7]));
    ((int4*)&Al[so])[1] = make_int4(pk(l[8],l[9]), pk(l[10],l[11]), pk(l[12],l[13]), pk(l[14],l[15]));
    *(int4*)&Bh[so] = bh0; *(int4*)&Bh[so + 8] = bh1;
    *(int4*)&Bl[so] = bl0; *(int4*)&Bl[so + 8] = bl1;
    __syncthreads();

    bf16x8 afh[4], afl[4], bfh[4], bfl[4];
    #pragma unroll
    for (int i = 0; i < 4; ++i) {
      const int ai = (wr + i * 16 + fm) * 32 + fq * 8;
      const int bi = (wc + i * 16 + fm) * 32 + fq * 8;
      afh[i] = *(const bf16x8*)&Ah[ai];
      afl[i] = *(const bf16x8*)&Al[ai];
      bfh[i] = *(const bf16x8*)&Bh[bi];
      bfl[i] = *(const bf16x8*)&Bl[bi];
    }
    #pragma unroll
    for (int mi = 0; mi < 4; ++mi)
      #pragma unroll
      for (int ni = 0; ni < 4; ++ni) {
        acc[mi][ni] = __builtin_amdgcn_mfma_f32_16x16x32_bf16(afh[mi], bfl[ni], acc[mi][ni], 0, 0, 0);
        acc[mi][ni] = __builtin_amdgcn_mfma_f32_16x16x32_bf16(afl[mi], bfh[ni], acc[mi][ni], 0, 0, 0);
        acc[mi][ni] = __builtin_amdgcn_mfma_f32_16x16x32_bf16(afh[mi], bfh[ni], acc[mi][ni], 0, 0, 0);
      }
  }

  float* Cb = (bx < 2) ? Kw : Vw;
  const int cb = ((bx & 1) << 7) + wc;
  #pragma unroll
  for (int mi = 0; mi < 4; ++mi) {
    #pragma unroll
    for (int r = 0; r < 4; ++r) {
      const int row = by * 128 + wr + mi * 16 + fq * 4 + r;
      if (row < 32832) {
        float* crow = Cb + (size_t)row * 256 + cb;
        #pragma unroll
        for (int ni = 0; ni < 4; ++ni)
          crow[ni * 16 + fm] = acc[mi][ni][r];
      }
    }
  }
}

// ---------------------------------------------------------------------------
// Wide tiled fp32 GEMM (Q and Wc projections): C[rows x 256] = A @ W (+bias)
// ---------------------------------------------------------------------------
template<int MODE>
__global__ __launch_bounds__(256) void gemm_wide(
    const float* __restrict__ A, const float* __restrict__ jobs,
    const float* __restrict__ skip, const float* __restrict__ W1,
    const float* __restrict__ bias, float* __restrict__ C1)
{
  __shared__ float As[16 * LDT];
  __shared__ float Bs[16 * LDB];
  const int tid = threadIdx.x;
  const int bx = blockIdx.x, by = blockIdx.y;

  const float* W = W1; float* C = C1; const int col0 = bx * 128;

  const int a_row = tid >> 2;
  const int a_k4  = (tid & 3) << 2;
  const int row = by * 64 + a_row;
  const float* arow;
  if (MODE == 0) {
    arow = A + ((size_t)row << 8);
  } else {
    const int bb = row / 513;
    const int t  = row - bb * 513;
    arow = (t == 0) ? skip : (jobs + ((size_t)(bb * 512 + t - 1) << 8));
  }

  const int b_k  = tid >> 4;
  const int b_c8 = (tid & 15) << 3;

  const int tr = tid >> 4, tc = tid & 15;
  float acc[4][8] = {};

  for (int k0 = 0; k0 < 256; k0 += 16) {
    const float4 av  = *(const float4*)(arow + k0 + a_k4);
    const float4 bv0 = *(const float4*)(W + ((size_t)(k0 + b_k) << 8) + col0 + b_c8);
    const float4 bv1 = *(const float4*)(W + ((size_t)(k0 + b_k) << 8) + col0 + b_c8 + 4);
    __syncthreads();
    As[(a_k4 + 0) * LDT + a_row] = av.x;
    As[(a_k4 + 1) * LDT + a_row] = av.y;
    As[(a_k4 + 2) * LDT + a_row] = av.z;
    As[(a_k4 + 3) * LDT + a_row] = av.w;
    *(float4*)&Bs[b_k * LDB + b_c8]     = bv0;
    *(float4*)&Bs[b_k * LDB + b_c8 + 4] = bv1;
    __syncthreads();
    #pragma unroll
    for (int k = 0; k < 16; ++k) {
      const float4 a  = *(const float4*)&As[k * LDT + (tr << 2)];
      const float4 b0 = *(const float4*)&Bs[k * LDB + (tc << 3)];
      const float4 b1 = *(const float4*)&Bs[k * LDB + (tc << 3) + 4];
      const float aa[4] = {a.x, a.y, a.z, a.w};
      #pragma unroll
      for (int i = 0; i < 4; ++i) {
        acc[i][0] = fmaf(aa[i], b0.x, acc[i][0]);
        acc[i][1] = fmaf(aa[i], b0.y, acc[i][1]);
        acc[i][2] = fmaf(aa[i], b0.z, acc[i][2]);
        acc[i][3] = fmaf(aa[i], b0.w, acc[i][3]);
        acc[i][4] = fmaf(aa[i], b1.x, acc[i][4]);
        acc[i][5] = fmaf(aa[i], b1.y, acc[i][5]);
        acc[i][6] = fmaf(aa[i], b1.z, acc[i][6]);
        acc[i][7] = fmaf(aa[i], b1.w, acc[i][7]);
      }
    }
  }

  const int oc = col0 + (tc << 3);
  float4 bsa = make_float4(0.f,0.f,0.f,0.f), bsb = make_float4(0.f,0.f,0.f,0.f);
  if (bias) { bsa = *(const float4*)(bias + oc); bsb = *(const float4*)(bias + oc + 4); }
  #pragma unroll
  for (int i = 0; i < 4; ++i) {
    float* crow = C + ((size_t)(by * 64 + (tr << 2) + i) << 8) + oc;
    float4 o0, o1;
    o0.x = acc[i][0]+bsa.x; o0.y = acc[i][1]+bsa.y; o0.z = acc[i][2]+bsa.z; o0.w = acc[i][3]+bsa.w;
    o1.x = acc[i][4]+bsb.x; o1.y = acc[i][5]+bsb.y; o1.z = acc[i][6]+bsb.z; o1.w = acc[i][7]+bsb.w;
    *(float4*)crow = o0; *(float4*)(crow + 4) = o1;
  }
}

// ---------------------------------------------------------------------------
// Attention partials v3: round-4 structure (grid (16,64,2), 128 thr, thread=m,
// ALL addressing block-uniform -> compiler scalarizes K/V loads to s_load),
// t-loop unrolled x2 to amortize the per-batch lgkmcnt(0) wait.
// ---------------------------------------------------------------------------
__global__ __launch_bounds__(128) void attn_part(
    const float* __restrict__ Q, const float* __restrict__ K,
    const float* __restrict__ V, float* __restrict__ Opart,
    float* __restrict__ Lpart)
{
  const int h = blockIdx.x, b = blockIdx.y, c = blockIdx.z;
  const int m = threadIdx.x;
  const int ts = c ? 257 : 0;
  const int te = c ? 513 : 257;

  float q[16];
  {
    const float* qp = Q + ((size_t)(b * 128 + m) << 8) + h * 16;
    #pragma unroll
    for (int i = 0; i < 16; i += 4) {
      const float4 v = *(const float4*)(qp + i);
      q[i] = v.x * 0.25f; q[i+1] = v.y * 0.25f;
      q[i+2] = v.z * 0.25f; q[i+3] = v.w * 0.25f;
    }
  }

  float l = 0.f, o[16] = {};
  const float* kp = K + ((size_t)(b * 513 + ts) << 8) + h * 16;
  const float* vp = V + ((size_t)(b * 513 + ts) << 8) + h * 16;

  int t = ts;
  for (; t + 1 < te; t += 2) {
    // 2 K rows + 2 V rows, all uniform addresses -> one scalar-load batch
    const float4 ka0 = *(const float4*)(kp);
    const float4 ka1 = *(const float4*)(kp + 4);
    const float4 ka2 = *(const float4*)(kp + 8);
    const float4 ka3 = *(const float4*)(kp + 12);
    const float4 kb0 = *(const float4*)(kp + 256);
    const float4 kb1 = *(const float4*)(kp + 260);
    const float4 kb2 = *(const float4*)(kp + 264);
    const float4 kb3 = *(const float4*)(kp + 268);
    const float4 va0 = *(const float4*)(vp);
    const float4 va1 = *(const float4*)(vp + 4);
    const float4 va2 = *(const float4*)(vp + 8);
    const float4 va3 = *(const float4*)(vp + 12);
    const float4 vb0 = *(const float4*)(vp + 256);
    const float4 vb1 = *(const float4*)(vp + 260);
    const float4 vb2 = *(const float4*)(vp + 264);
    const float4 vb3 = *(const float4*)(vp + 268);

    float s0 = q[0]*ka0.x;  s0 = fmaf(q[1],ka0.y,s0);  s0 = fmaf(q[2],ka0.z,s0);  s0 = fmaf(q[3],ka0.w,s0);
    float s1 = q[4]*ka1.x;  s1 = fmaf(q[5],ka1.y,s1);  s1 = fmaf(q[6],ka1.z,s1);  s1 = fmaf(q[7],ka1.w,s1);
    float s2 = q[8]*ka2.x;  s2 = fmaf(q[9],ka2.y,s2);  s2 = fmaf(q[10],ka2.z,s2); s2 = fmaf(q[11],ka2.w,s2);
    float s3 = q[12]*ka3.x; s3 = fmaf(q[13],ka3.y,s3); s3 = fmaf(q[14],ka3.z,s3); s3 = fmaf(q[15],ka3.w,s3);
    float u0 = q[0]*kb0.x;  u0 = fmaf(q[1],kb0.y,u0);  u0 = fmaf(q[2],kb0.z,u0);  u0 = fmaf(q[3],kb0.w,u0);
    float u1 = q[4]*kb1.x;  u1 = fmaf(q[5],kb1.y,u1);  u1 = fmaf(q[6],kb1.z,u1);  u1 = fmaf(q[7],kb1.w,u1);
    float u2 = q[8]*kb2.x;  u2 = fmaf(q[9],kb2.y,u2);  u2 = fmaf(q[10],kb2.z,u2); u2 = fmaf(q[11],kb2.w,u2);
    float u3 = q[12]*kb3.x; u3 = fmaf(q[13],kb3.y,u3); u3 = fmaf(q[14],kb3.z,u3); u3 = fmaf(q[15],kb3.w,u3);
    const float ea = __expf((s0 + s1) + (s2 + s3));
    const float eb = __expf((u0 + u1) + (u2 + u3));
    l += ea + eb;
    o[0]  = fmaf(ea, va0.x, o[0]);  o[0]  = fmaf(eb, vb0.x, o[0]);
    o[1]  = fmaf(ea, va0.y, o[1]);  o[1]  = fmaf(eb, vb0.y, o[1]);
    o[2]  = fmaf(ea, va0.z, o[2]);  o[2]  = fmaf(eb, vb0.z, o[2]);
    o[3]  = fmaf(ea, va0.w, o[3]);  o[3]  = fmaf(eb, vb0.w, o[3]);
    o[4]  = fmaf(ea, va1.x, o[4]);  o[4]  = fmaf(eb, vb1.x, o[4]);
    o[5]  = fmaf(ea, va1.y, o[5]);  o[5]  = fmaf(eb, vb1.y, o[5]);
    o[6]  = fmaf(ea, va1.z, o[6]);  o[6]  = fmaf(eb, vb1.z, o[6]);
    o[7]  = fmaf(ea, va1.w, o[7]);  o[7]  = fmaf(eb, vb1.w, o[7]);
    o[8]  = fmaf(ea, va2.x, o[8]);  o[8]  = fmaf(eb, vb2.x, o[8]);
    o[9]  = fmaf(ea, va2.y, o[9]);  o[9]  = fmaf(eb, vb2.y, o[9]);
    o[10] = fmaf(ea, va2.z, o[10]); o[10] = fmaf(eb, vb2.z, o[10]);
    o[11] = fmaf(ea, va2.w, o[11]); o[11] = fmaf(eb, vb2.w, o[11]);
    o[12] = fmaf(ea, va3.x, o[12]); o[12] = fmaf(eb, vb3.x, o[12]);
    o[13] = fmaf(ea, va3.y, o[13]); o[13] = fmaf(eb, vb3.y, o[13]);
    o[14] = fmaf(ea, va3.z, o[14]); o[14] = fmaf(eb, vb3.z, o[14]);
    o[15] = fmaf(ea, va3.w, o[15]); o[15] = fmaf(eb, vb3.w, o[15]);
    kp += 512; vp += 512;
  }
  if (t < te) {   // odd tail (c=0 only: 257 iterations)
    const float4 k0 = *(const float4*)(kp);
    const float4 k1 = *(const float4*)(kp + 4);
    const float4 k2 = *(const float4*)(kp + 8);
    const float4 k3 = *(const float4*)(kp + 12);
    const float4 v0 = *(const float4*)(vp);
    const float4 v1 = *(const float4*)(vp + 4);
    const float4 v2 = *(const float4*)(vp + 8);
    const float4 v3 = *(const float4*)(vp + 12);
    float s0 = q[0]*k0.x;  s0 = fmaf(q[1],k0.y,s0);  s0 = fmaf(q[2],k0.z,s0);  s0 = fmaf(q[3],k0.w,s0);
    float s1 = q[4]*k1.x;  s1 = fmaf(q[5],k1.y,s1);  s1 = fmaf(q[6],k1.z,s1);  s1 = fmaf(q[7],k1.w,s1);
    float s2 = q[8]*k2.x;  s2 = fmaf(q[9],k2.y,s2);  s2 = fmaf(q[10],k2.z,s2); s2 = fmaf(q[11],k2.w,s2);
    float s3 = q[12]*k3.x; s3 = fmaf(q[13],k3.y,s3); s3 = fmaf(q[14],k3.z,s3); s3 = fmaf(q[15],k3.w,s3);
    const float e = __expf((s0 + s1) + (s2 + s3));
    l += e;
    o[0]  = fmaf(e, v0.x, o[0]);  o[1]  = fmaf(e, v0.y, o[1]);
    o[2]  = fmaf(e, v0.z, o[2]);  o[3]  = fmaf(e, v0.w, o[3]);
    o[4]  = fmaf(e, v1.x, o[4]);  o[5]  = fmaf(e, v1.y, o[5]);
    o[6]  = fmaf(e, v1.z, o[6]);  o[7]  = fmaf(e, v1.w, o[7]);
    o[8]  = fmaf(e, v2.x, o[8]);  o[9]  = fmaf(e, v2.y, o[9]);
    o[10] = fmaf(e, v2.z, o[10]); o[11] = fmaf(e, v2.w, o[11]);
    o[12] = fmaf(e, v3.x, o[12]); o[13] = fmaf(e, v3.y, o[13]);
    o[14] = fmaf(e, v3.z, o[14]); o[15] = fmaf(e, v3.w, o[15]);
  }

  const int idx = (b * 16 + h) * 128 + m;
  float* op = Opart + ((size_t)(c * 131072 + idx) << 4);
  #pragma unroll
  for (int i = 0; i < 16; i += 4) {
    float4 v; v.x = o[i]; v.y = o[i+1]; v.z = o[i+2]; v.w = o[i+3];
    *(float4*)(op + i) = v;
  }
  Lpart[c * 131072 + idx] = l;
}

// Combine 2 T-chunks: o = (o0+o1)/(l0+l1), write out_concat (B,M,H*D).
__global__ __launch_bounds__(256) void attn_combine(
    const float* __restrict__ Opart, const float* __restrict__ Lpart,
    float* __restrict__ OC)
{
  const int gid = blockIdx.x * 256 + threadIdx.x;   // < 131072
  const float* p0 = Opart + ((size_t)gid << 4);
  const float* p1 = Opart + ((size_t)(131072 + gid) << 4);
  const float inv = 1.f / (Lpart[gid] + Lpart[131072 + gid]);
  const int m = gid & 127, bh = gid >> 7, h = bh & 15, b = bh >> 4;
  float* op = OC + ((size_t)(b * 128 + m) << 8) + h * 16;
  #pragma unroll
  for (int i = 0; i < 16; i += 4) {
    const float4 a = *(const float4*)(p0 + i);
    const float4 c = *(const float4*)(p1 + i);
    float4 v;
    v.x = (a.x + c.x) * inv; v.y = (a.y + c.y) * inv;
    v.z = (a.z + c.z) * inv; v.w = (a.w + c.w) * inv;
    *(float4*)(op + i) = v;
  }
}

// ---------------------------------------------------------------------------
// Logits GEMM, fused exp(10*tanh(x/16)+mask-10) + deterministic partials.
// ---------------------------------------------------------------------------
__global__ __launch_bounds__(256) void logits_gemm(
    const float* __restrict__ MH, const float* __restrict__ jobs,
    const float* __restrict__ skip, const float* __restrict__ mask,
    float* __restrict__ out, float* __restrict__ partials)
{
  __shared__ float As[16 * LDT];
  __shared__ float Bs[16 * LDT];
  __shared__ float red[4];
  const int tid = threadIdx.x;
  const int b = blockIdx.z;

  const int m_l = tid >> 2;
  const int kk4 = (tid & 3) << 2;
  const float* arow = MH + ((size_t)(b * 128 + blockIdx.y * 64 + m_l) << 8);

  const int t_g = blockIdx.x * 64 + m_l;
  const float* brow = nullptr;
  if (t_g < 513)
    brow = (t_g == 0) ? skip : (jobs + ((size_t)(b * 512 + t_g - 1) << 8));

  const int tr = tid >> 4, tc = tid & 15;
  float acc[4][4] = {};

  for (int k0 = 0; k0 < 256; k0 += 16) {
    const float4 av = *(const float4*)(arow + k0 + kk4);
    float4 bv = make_float4(0.f, 0.f, 0.f, 0.f);
    if (brow) bv = *(const float4*)(brow + k0 + kk4);
    __syncthreads();
    As[(kk4 + 0) * LDT + m_l] = av.x;
    As[(kk4 + 1) * LDT + m_l] = av.y;
    As[(kk4 + 2) * LDT + m_l] = av.z;
    As[(kk4 + 3) * LDT + m_l] = av.w;
    Bs[(kk4 + 0) * LDT + m_l] = bv.x;
    Bs[(kk4 + 1) * LDT + m_l] = bv.y;
    Bs[(kk4 + 2) * LDT + m_l] = bv.z;
    Bs[(kk4 + 3) * LDT + m_l] = bv.w;
    __syncthreads();
    #pragma unroll
    for (int k = 0; k < 16; ++k) {
      const float4 a  = *(const float4*)&As[k * LDT + (tr << 2)];
      const float4 b4 = *(const float4*)&Bs[k * LDT + (tc << 2)];
      const float aa[4] = {a.x, a.y, a.z, a.w};
      #pragma unroll
      for (int i = 0; i < 4; ++i) {
        acc[i][0] = fmaf(aa[i], b4.x, acc[i][0]);
        acc[i][1] = fmaf(aa[i], b4.y, acc[i][1]);
        acc[i][2] = fmaf(aa[i], b4.z, acc[i][2]);
        acc[i][3] = fmaf(aa[i], b4.w, acc[i][3]);
      }
    }
  }

  float lsum = 0.f;
  #pragma unroll
  for (int i = 0; i < 4; ++i) {
    const int mm = blockIdx.y * 64 + (tr << 2) + i;
    #pragma unroll
    for (int j = 0; j < 4; ++j) {
      const int tt = blockIdx.x * 64 + (tc << 2) + j;
      if (tt < 513) {
        const float lg = 10.f * tanhf(acc[i][j] * 0.0625f)
                       + mask[((size_t)(b * 128 + mm)) * 513 + tt];
        const float e = __expf(lg - 10.f);
        out[(size_t)b * 65664 + (size_t)mm * 513 + tt] = e;
        lsum += e;
      }
    }
  }
  #pragma unroll
  for (int off = 32; off; off >>= 1) lsum += __shfl_xor(lsum, off);
  if ((tid & 63) == 0) red[tid >> 6] = lsum;
  __syncthreads();
  if (tid == 0)
    partials[b * 18 + blockIdx.x * 2 + blockIdx.y] =
        (red[0] + red[1]) + (red[2] + red[3]);
}

__global__ void sm_inv(const float* __restrict__ partials, float* __restrict__ invb)
{
  const int b = threadIdx.x;
  if (b < 64) {
    float s = 0.f;
    #pragma unroll
    for (int i = 0; i < 18; ++i) s += partials[b * 18 + i];
    invb[b] = 1.f / s;
  }
}

__global__ __launch_bounds__(256) void sm_norm(float* __restrict__ out,
                                               const float* __restrict__ invb)
{
  const int i4 = blockIdx.x * 256 + threadIdx.x;
  if (i4 < 1050624) {
    const int b = i4 / 16416;
    float4 v = ((float4*)out)[i4];
    const float s = invb[b];
    v.x *= s; v.y *= s; v.z *= s; v.w *= s;
    ((float4*)out)[i4] = v;
  }
}

// ---------------------------------------------------------------------------
extern "C" void kernel_launch(void* const* d_in, const int* in_sizes, int n_in,
                              void* d_out, int out_size, void* d_ws, size_t ws_size,
                              hipStream_t stream)
{
  const float* machine = (const float*)d_in[0];
  const float* jobs    = (const float*)d_in[1];
  const float* mask    = (const float*)d_in[2];
  const float* Wq      = (const float*)d_in[3];
  const float* Wk      = (const float*)d_in[4];
  const float* Wv      = (const float*)d_in[5];
  const float* Wc      = (const float*)d_in[6];
  const float* bc      = (const float*)d_in[7];
  const float* skip    = (const float*)d_in[8];

  // Workspace (floats). Peak 23,101,440 f = 92.4 MB (same as r1/r3/r4).
  float* ws       = (float*)d_ws;
  float* Qw       = ws;
  float* Kw       = ws + 2097152;
  float* Vw       = ws + 10502144;
  unsigned short* Wth = (unsigned short*)(ws + 18907136);  // dead before Opart written
  unsigned short* Wtl = Wth + 131072;
  float* Opart    = ws + 18907136;
  float* MH       = ws + 18907136;     // overlays Opart chunk0 (dead by then)
  float* partials = ws + 2097152;      // overlays Kw (dead after attn_part)
  float* invb     = partials + 1152;
  float* OC       = Qw;
  float* out      = (float*)d_out;
  float* Lpart    = out;               // dead before logits writes

  // Q = machine @ Wq3 (fp32)
  gemm_wide<0><<<dim3(2, 128), 256, 0, stream>>>(
      machine, nullptr, nullptr, Wq, nullptr, Qw);
  // W split/transpose, then K|V = vjobs @ [Wk|Wv] via split-bf16 MFMA
  prep_wt<<<512, 256, 0, stream>>>(Wk, Wv, Wth, Wtl);
  gemm_kv_mfma<<<dim3(4, 257), 256, 0, stream>>>(jobs, skip, Wth, Wtl, Kw, Vw);
  // attention partials + combine
  attn_part<<<dim3(16, 64, 2), 128, 0, stream>>>(Qw, Kw, Vw, Opart, Lpart);
  attn_combine<<<512, 256, 0, stream>>>(Opart, Lpart, OC);
  // mh = out_concat @ Wc + bc (fp32)
  gemm_wide<0><<<dim3(2, 128), 256, 0, stream>>>(
      OC, nullptr, nullptr, Wc, bc, MH);
  // exp(logits-10) + partials
  logits_gemm<<<dim3(9, 2, 64), 256, 0, stream>>>(MH, jobs, skip, mask, out, partials);
  sm_inv<<<1, 64, 0, stream>>>(partials, invb);
  sm_norm<<<4104, 256, 0, stream>>>(out, invb);
}

// Round 7
// 378.231 us; speedup vs baseline: 1.4823x; 1.0084x over previous
//
#include <hip/hip_runtime.h>
#include <math.h>

// B=64, M=128, J=512, T=513, E=256, H=16, D=16; out (64, 65664) fp32.

#define LDT 68    // 64-row A-tile LDS leading dim (fp32 gemms)
#define LDB 132   // 128-col B-tile LDS leading dim (fp32 gemms)

typedef __attribute__((ext_vector_type(8))) short bf16x8;   // 8 bf16 = 4 VGPR
typedef __attribute__((ext_vector_type(4))) float f32x4;    // MFMA acc

static __device__ inline unsigned short f2bf(float x) {     // RNE fp32->bf16
  unsigned u = __float_as_uint(x);
  return (unsigned short)((u + 0x7fffu + ((u >> 16) & 1u)) >> 16);
}
static __device__ inline float bf2f(unsigned short h) {
  return __uint_as_float(((unsigned)h) << 16);
}
static __device__ inline unsigned pk(unsigned short a, unsigned short b) {
  return (unsigned)a | ((unsigned)b << 16);
}

// ---------------------------------------------------------------------------
// One-time W split+transpose: Wt[col][k] (bf16 hi/lo), col 0..255 = Wk cols,
// 256..511 = Wv cols. grid 512 blocks x 256 thr (thread = k).
// ---------------------------------------------------------------------------
__global__ void prep_wt(const float* __restrict__ Wk, const float* __restrict__ Wv,
                        unsigned short* __restrict__ Wth, unsigned short* __restrict__ Wtl)
{
  const int c = blockIdx.x, k = threadIdx.x;
  const float x = (c < 256) ? Wk[k * 256 + c] : Wv[k * 256 + (c - 256)];
  const unsigned short h = f2bf(x);
  Wth[c * 256 + k] = h;
  Wtl[c * 256 + k] = f2bf(x - bf2f(h));
}

// ---------------------------------------------------------------------------
// Split-bf16 MFMA GEMM: C(32832 x 512) = vjobs(32832 x 256) @ [Wk|Wv].
// 128x128 tile, 256 thr = 4 waves (2x2, each 64x64 via 4x4 16x16x32 tiles).
// C = Ah*Bh + Ah*Bl + Al*Bh  (error ~2^-17, fp32-grade for this use).
// ---------------------------------------------------------------------------
__global__ __launch_bounds__(256) void gemm_kv_mfma(
    const float* __restrict__ jobs, const float* __restrict__ skip,
    const unsigned short* __restrict__ Wth, const unsigned short* __restrict__ Wtl,
    float* __restrict__ Kw, float* __restrict__ Vw)
{
  __shared__ short Ah[128 * 32], Al[128 * 32];   // [row][k] bf16, 8KB each
  __shared__ short Bh[128 * 32], Bl[128 * 32];   // [col][k] bf16
  const int tid = threadIdx.x;
  const int bx = blockIdx.x, by = blockIdx.y;

  const int r16 = tid >> 1;
  const int h16 = (tid & 1) << 4;
  int rg = by * 128 + r16; if (rg > 32831) rg = 32831;
  const int bb = rg / 513, tt = rg - bb * 513;
  const float* arow = (tt == 0) ? skip : (jobs + ((size_t)(bb * 512 + tt - 1) << 8));
  const unsigned short* bhrow = Wth + ((size_t)(bx * 128 + r16) << 8);
  const unsigned short* blrow = Wtl + ((size_t)(bx * 128 + r16) << 8);

  const int w = tid >> 6, lane = tid & 63;
  const int wr = (w >> 1) << 6, wc = (w & 1) << 6;
  const int fm = lane & 15, fq = lane >> 4;

  f32x4 acc[4][4] = {};

  for (int kk = 0; kk < 256; kk += 32) {
    const float4 a0 = *(const float4*)(arow + kk + h16);
    const float4 a1 = *(const float4*)(arow + kk + h16 + 4);
    const float4 a2 = *(const float4*)(arow + kk + h16 + 8);
    const float4 a3 = *(const float4*)(arow + kk + h16 + 12);
    const int4 bh0 = *(const int4*)(bhrow + kk + h16);
    const int4 bh1 = *(const int4*)(bhrow + kk + h16 + 8);
    const int4 bl0 = *(const int4*)(blrow + kk + h16);
    const int4 bl1 = *(const int4*)(blrow + kk + h16 + 8);

    unsigned short h[16], l[16];
    const float av[16] = {a0.x,a0.y,a0.z,a0.w, a1.x,a1.y,a1.z,a1.w,
                          a2.x,a2.y,a2.z,a2.w, a3.x,a3.y,a3.z,a3.w};
    #pragma unroll
    for (int i = 0; i < 16; ++i) {
      h[i] = f2bf(av[i]);
      l[i] = f2bf(av[i] - bf2f(h[i]));
    }

    __syncthreads();
    const int so = r16 * 32 + h16;
    ((int4*)&Ah[so])[0] = make_int4(pk(h[0],h[1]), pk(h[2],h[3]), pk(h[4],h[5]), pk(h[6],h[7]));
    ((int4*)&Ah[so])[1] = make_int4(pk(h[8],h[9]), pk(h[10],h[11]), pk(h[12],h[13]), pk(h[14],h[15]));
    ((int4*)&Al[so])[0] = make_int4(pk(l[0],l[1]), pk(l[2],l[3]), pk(l[4],l[5]), pk(l[6],l[7]));
    ((int4*)&Al[so])[1] = make_int4(pk(l[8],l[9]), pk(l[10],l[11]), pk(l[12],l[13]), pk(l[14],l[15]));
    *(int4*)&Bh[so] = bh0; *(int4*)&Bh[so + 8] = bh1;
    *(int4*)&Bl[so] = bl0; *(int4*)&Bl[so + 8] = bl1;
    __syncthreads();

    bf16x8 afh[4], afl[4], bfh[4], bfl[4];
    #pragma unroll
    for (int i = 0; i < 4; ++i) {
      const int ai = (wr + i * 16 + fm) * 32 + fq * 8;
      const int bi = (wc + i * 16 + fm) * 32 + fq * 8;
      afh[i] = *(const bf16x8*)&Ah[ai];
      afl[i] = *(const bf16x8*)&Al[ai];
      bfh[i] = *(const bf16x8*)&Bh[bi];
      bfl[i] = *(const bf16x8*)&Bl[bi];
    }
    #pragma unroll
    for (int mi = 0; mi < 4; ++mi)
      #pragma unroll
      for (int ni = 0; ni < 4; ++ni) {
        acc[mi][ni] = __builtin_amdgcn_mfma_f32_16x16x32_bf16(afh[mi], bfl[ni], acc[mi][ni], 0, 0, 0);
        acc[mi][ni] = __builtin_amdgcn_mfma_f32_16x16x32_bf16(afl[mi], bfh[ni], acc[mi][ni], 0, 0, 0);
        acc[mi][ni] = __builtin_amdgcn_mfma_f32_16x16x32_bf16(afh[mi], bfh[ni], acc[mi][ni], 0, 0, 0);
      }
  }

  float* Cb = (bx < 2) ? Kw : Vw;
  const int cb = ((bx & 1) << 7) + wc;
  #pragma unroll
  for (int mi = 0; mi < 4; ++mi) {
    #pragma unroll
    for (int r = 0; r < 4; ++r) {
      const int row = by * 128 + wr + mi * 16 + fq * 4 + r;
      if (row < 32832) {
        float* crow = Cb + (size_t)row * 256 + cb;
        #pragma unroll
        for (int ni = 0; ni < 4; ++ni)
          crow[ni * 16 + fm] = acc[mi][ni][r];
      }
    }
  }
}

// ---------------------------------------------------------------------------
// Wide tiled fp32 GEMM (Q and Wc projections): C[rows x 256] = A @ W (+bias)
// ---------------------------------------------------------------------------
template<int MODE>
__global__ __launch_bounds__(256) void gemm_wide(
    const float* __restrict__ A, const float* __restrict__ jobs,
    const float* __restrict__ skip, const float* __restrict__ W1,
    const float* __restrict__ bias, float* __restrict__ C1)
{
  __shared__ float As[16 * LDT];
  __shared__ float Bs[16 * LDB];
  const int tid = threadIdx.x;
  const int bx = blockIdx.x, by = blockIdx.y;

  const float* W = W1; float* C = C1; const int col0 = bx * 128;

  const int a_row = tid >> 2;
  const int a_k4  = (tid & 3) << 2;
  const int row = by * 64 + a_row;
  const float* arow;
  if (MODE == 0) {
    arow = A + ((size_t)row << 8);
  } else {
    const int bb = row / 513;
    const int t  = row - bb * 513;
    arow = (t == 0) ? skip : (jobs + ((size_t)(bb * 512 + t - 1) << 8));
  }

  const int b_k  = tid >> 4;
  const int b_c8 = (tid & 15) << 3;

  const int tr = tid >> 4, tc = tid & 15;
  float acc[4][8] = {};

  for (int k0 = 0; k0 < 256; k0 += 16) {
    const float4 av  = *(const float4*)(arow + k0 + a_k4);
    const float4 bv0 = *(const float4*)(W + ((size_t)(k0 + b_k) << 8) + col0 + b_c8);
    const float4 bv1 = *(const float4*)(W + ((size_t)(k0 + b_k) << 8) + col0 + b_c8 + 4);
    __syncthreads();
    As[(a_k4 + 0) * LDT + a_row] = av.x;
    As[(a_k4 + 1) * LDT + a_row] = av.y;
    As[(a_k4 + 2) * LDT + a_row] = av.z;
    As[(a_k4 + 3) * LDT + a_row] = av.w;
    *(float4*)&Bs[b_k * LDB + b_c8]     = bv0;
    *(float4*)&Bs[b_k * LDB + b_c8 + 4] = bv1;
    __syncthreads();
    #pragma unroll
    for (int k = 0; k < 16; ++k) {
      const float4 a  = *(const float4*)&As[k * LDT + (tr << 2)];
      const float4 b0 = *(const float4*)&Bs[k * LDB + (tc << 3)];
      const float4 b1 = *(const float4*)&Bs[k * LDB + (tc << 3) + 4];
      const float aa[4] = {a.x, a.y, a.z, a.w};
      #pragma unroll
      for (int i = 0; i < 4; ++i) {
        acc[i][0] = fmaf(aa[i], b0.x, acc[i][0]);
        acc[i][1] = fmaf(aa[i], b0.y, acc[i][1]);
        acc[i][2] = fmaf(aa[i], b0.z, acc[i][2]);
        acc[i][3] = fmaf(aa[i], b0.w, acc[i][3]);
        acc[i][4] = fmaf(aa[i], b1.x, acc[i][4]);
        acc[i][5] = fmaf(aa[i], b1.y, acc[i][5]);
        acc[i][6] = fmaf(aa[i], b1.z, acc[i][6]);
        acc[i][7] = fmaf(aa[i], b1.w, acc[i][7]);
      }
    }
  }

  const int oc = col0 + (tc << 3);
  float4 bsa = make_float4(0.f,0.f,0.f,0.f), bsb = make_float4(0.f,0.f,0.f,0.f);
  if (bias) { bsa = *(const float4*)(bias + oc); bsb = *(const float4*)(bias + oc + 4); }
  #pragma unroll
  for (int i = 0; i < 4; ++i) {
    float* crow = C + ((size_t)(by * 64 + (tr << 2) + i) << 8) + oc;
    float4 o0, o1;
    o0.x = acc[i][0]+bsa.x; o0.y = acc[i][1]+bsa.y; o0.z = acc[i][2]+bsa.z; o0.w = acc[i][3]+bsa.w;
    o1.x = acc[i][4]+bsb.x; o1.y = acc[i][5]+bsb.y; o1.z = acc[i][6]+bsb.z; o1.w = acc[i][7]+bsb.w;
    *(float4*)crow = o0; *(float4*)(crow + 4) = o1;
  }
}

// ---------------------------------------------------------------------------
// Attention partials v4: ONE wave per (h, b, c); each lane owns m and m+64.
// K/V addresses depend only on blockIdx + loop var -> fully wave-uniform ->
// compiler scalarizes to s_load; each K/V byte crosses the scalar path ONCE
// (r4/r6 had 2 m-waves per block fetching the same bytes twice).
// ---------------------------------------------------------------------------
__global__ __launch_bounds__(64) void attn_part(
    const float* __restrict__ Q, const float* __restrict__ K,
    const float* __restrict__ V, float* __restrict__ Opart,
    float* __restrict__ Lpart)
{
  const int h = blockIdx.x, b = blockIdx.y, c = blockIdx.z;
  const int m = threadIdx.x;          // 0..63 ; lane handles m and m+64
  const int ts = c ? 257 : 0;
  const int te = c ? 513 : 257;

  float q0[16], q1[16];
  {
    const float* qp0 = Q + ((size_t)(b * 128 + m) << 8) + h * 16;
    const float* qp1 = qp0 + (64 << 8);
    #pragma unroll
    for (int i = 0; i < 16; i += 4) {
      const float4 a = *(const float4*)(qp0 + i);
      const float4 d = *(const float4*)(qp1 + i);
      q0[i] = a.x * 0.25f; q0[i+1] = a.y * 0.25f; q0[i+2] = a.z * 0.25f; q0[i+3] = a.w * 0.25f;
      q1[i] = d.x * 0.25f; q1[i+1] = d.y * 0.25f; q1[i+2] = d.z * 0.25f; q1[i+3] = d.w * 0.25f;
    }
  }

  float l0 = 0.f, l1 = 0.f, o0[16] = {}, o1[16] = {};
  const float* kp = K + ((size_t)(b * 513 + ts) << 8) + h * 16;
  const float* vp = V + ((size_t)(b * 513 + ts) << 8) + h * 16;

#define DOT16(Q_, P_, S_) do { \
    float s0_ = Q_[0]*(P_)[0];  s0_ = fmaf(Q_[1],(P_)[1],s0_);  s0_ = fmaf(Q_[2],(P_)[2],s0_);  s0_ = fmaf(Q_[3],(P_)[3],s0_); \
    float s1_ = Q_[4]*(P_)[4];  s1_ = fmaf(Q_[5],(P_)[5],s1_);  s1_ = fmaf(Q_[6],(P_)[6],s1_);  s1_ = fmaf(Q_[7],(P_)[7],s1_); \
    float s2_ = Q_[8]*(P_)[8];  s2_ = fmaf(Q_[9],(P_)[9],s2_);  s2_ = fmaf(Q_[10],(P_)[10],s2_); s2_ = fmaf(Q_[11],(P_)[11],s2_); \
    float s3_ = Q_[12]*(P_)[12]; s3_ = fmaf(Q_[13],(P_)[13],s3_); s3_ = fmaf(Q_[14],(P_)[14],s3_); s3_ = fmaf(Q_[15],(P_)[15],s3_); \
    S_ = (s0_ + s1_) + (s2_ + s3_); } while (0)

#define ACC16(O_, E_, P_) do { \
    O_[0]=fmaf(E_,(P_)[0],O_[0]);   O_[1]=fmaf(E_,(P_)[1],O_[1]); \
    O_[2]=fmaf(E_,(P_)[2],O_[2]);   O_[3]=fmaf(E_,(P_)[3],O_[3]); \
    O_[4]=fmaf(E_,(P_)[4],O_[4]);   O_[5]=fmaf(E_,(P_)[5],O_[5]); \
    O_[6]=fmaf(E_,(P_)[6],O_[6]);   O_[7]=fmaf(E_,(P_)[7],O_[7]); \
    O_[8]=fmaf(E_,(P_)[8],O_[8]);   O_[9]=fmaf(E_,(P_)[9],O_[9]); \
    O_[10]=fmaf(E_,(P_)[10],O_[10]); O_[11]=fmaf(E_,(P_)[11],O_[11]); \
    O_[12]=fmaf(E_,(P_)[12],O_[12]); O_[13]=fmaf(E_,(P_)[13],O_[13]); \
    O_[14]=fmaf(E_,(P_)[14],O_[14]); O_[15]=fmaf(E_,(P_)[15],O_[15]); } while (0)

  int t = ts;
  for (; t + 1 < te; t += 2) {
    float ea0, eb0, ea1, eb1;
    {
      const float* ka = kp;          // row t   (uniform -> SGPRs)
      const float* kb = kp + 256;    // row t+1
      DOT16(q0, ka, ea0); DOT16(q0, kb, eb0);
      DOT16(q1, ka, ea1); DOT16(q1, kb, eb1);
    }
    ea0 = __expf(ea0); eb0 = __expf(eb0);
    ea1 = __expf(ea1); eb1 = __expf(eb1);
    l0 += ea0 + eb0; l1 += ea1 + eb1;
    {
      const float* va = vp;
      const float* vb = vp + 256;
      ACC16(o0, ea0, va); ACC16(o0, eb0, vb);
      ACC16(o1, ea1, va); ACC16(o1, eb1, vb);
    }
    kp += 512; vp += 512;
  }
  if (t < te) {   // odd tail (c=0 only: 257 iterations)
    float s0, s1;
    DOT16(q0, kp, s0); DOT16(q1, kp, s1);
    const float e0 = __expf(s0), e1 = __expf(s1);
    l0 += e0; l1 += e1;
    ACC16(o0, e0, vp); ACC16(o1, e1, vp);
  }

  const int idx = (b * 16 + h) * 128 + m;
  float* op0 = Opart + ((size_t)(c * 131072 + idx) << 4);
  float* op1 = Opart + ((size_t)(c * 131072 + idx + 64) << 4);
  #pragma unroll
  for (int i = 0; i < 16; i += 4) {
    float4 v0; v0.x = o0[i]; v0.y = o0[i+1]; v0.z = o0[i+2]; v0.w = o0[i+3];
    float4 v1; v1.x = o1[i]; v1.y = o1[i+1]; v1.z = o1[i+2]; v1.w = o1[i+3];
    *(float4*)(op0 + i) = v0;
    *(float4*)(op1 + i) = v1;
  }
  Lpart[c * 131072 + idx]      = l0;
  Lpart[c * 131072 + idx + 64] = l1;
#undef DOT16
#undef ACC16
}

// Combine 2 T-chunks: o = (o0+o1)/(l0+l1), write out_concat (B,M,H*D).
__global__ __launch_bounds__(256) void attn_combine(
    const float* __restrict__ Opart, const float* __restrict__ Lpart,
    float* __restrict__ OC)
{
  const int gid = blockIdx.x * 256 + threadIdx.x;   // < 131072
  const float* p0 = Opart + ((size_t)gid << 4);
  const float* p1 = Opart + ((size_t)(131072 + gid) << 4);
  const float inv = 1.f / (Lpart[gid] + Lpart[131072 + gid]);
  const int m = gid & 127, bh = gid >> 7, h = bh & 15, b = bh >> 4;
  float* op = OC + ((size_t)(b * 128 + m) << 8) + h * 16;
  #pragma unroll
  for (int i = 0; i < 16; i += 4) {
    const float4 a = *(const float4*)(p0 + i);
    const float4 c = *(const float4*)(p1 + i);
    float4 v;
    v.x = (a.x + c.x) * inv; v.y = (a.y + c.y) * inv;
    v.z = (a.z + c.z) * inv; v.w = (a.w + c.w) * inv;
    *(float4*)(op + i) = v;
  }
}

// ---------------------------------------------------------------------------
// Logits GEMM, fused exp(10*tanh(x/16)+mask-10) + deterministic partials.
// ---------------------------------------------------------------------------
__global__ __launch_bounds__(256) void logits_gemm(
    const float* __restrict__ MH, const float* __restrict__ jobs,
    const float* __restrict__ skip, const float* __restrict__ mask,
    float* __restrict__ out, float* __restrict__ partials)
{
  __shared__ float As[16 * LDT];
  __shared__ float Bs[16 * LDT];
  __shared__ float red[4];
  const int tid = threadIdx.x;
  const int b = blockIdx.z;

  const int m_l = tid >> 2;
  const int kk4 = (tid & 3) << 2;
  const float* arow = MH + ((size_t)(b * 128 + blockIdx.y * 64 + m_l) << 8);

  const int t_g = blockIdx.x * 64 + m_l;
  const float* brow = nullptr;
  if (t_g < 513)
    brow = (t_g == 0) ? skip : (jobs + ((size_t)(b * 512 + t_g - 1) << 8));

  const int tr = tid >> 4, tc = tid & 15;
  float acc[4][4] = {};

  for (int k0 = 0; k0 < 256; k0 += 16) {
    const float4 av = *(const float4*)(arow + k0 + kk4);
    float4 bv = make_float4(0.f, 0.f, 0.f, 0.f);
    if (brow) bv = *(const float4*)(brow + k0 + kk4);
    __syncthreads();
    As[(kk4 + 0) * LDT + m_l] = av.x;
    As[(kk4 + 1) * LDT + m_l] = av.y;
    As[(kk4 + 2) * LDT + m_l] = av.z;
    As[(kk4 + 3) * LDT + m_l] = av.w;
    Bs[(kk4 + 0) * LDT + m_l] = bv.x;
    Bs[(kk4 + 1) * LDT + m_l] = bv.y;
    Bs[(kk4 + 2) * LDT + m_l] = bv.z;
    Bs[(kk4 + 3) * LDT + m_l] = bv.w;
    __syncthreads();
    #pragma unroll
    for (int k = 0; k < 16; ++k) {
      const float4 a  = *(const float4*)&As[k * LDT + (tr << 2)];
      const float4 b4 = *(const float4*)&Bs[k * LDT + (tc << 2)];
      const float aa[4] = {a.x, a.y, a.z, a.w};
      #pragma unroll
      for (int i = 0; i < 4; ++i) {
        acc[i][0] = fmaf(aa[i], b4.x, acc[i][0]);
        acc[i][1] = fmaf(aa[i], b4.y, acc[i][1]);
        acc[i][2] = fmaf(aa[i], b4.z, acc[i][2]);
        acc[i][3] = fmaf(aa[i], b4.w, acc[i][3]);
      }
    }
  }

  float lsum = 0.f;
  #pragma unroll
  for (int i = 0; i < 4; ++i) {
    const int mm = blockIdx.y * 64 + (tr << 2) + i;
    #pragma unroll
    for (int j = 0; j < 4; ++j) {
      const int tt = blockIdx.x * 64 + (tc << 2) + j;
      if (tt < 513) {
        const float lg = 10.f * tanhf(acc[i][j] * 0.0625f)
                       + mask[((size_t)(b * 128 + mm)) * 513 + tt];
        const float e = __expf(lg - 10.f);
        out[(size_t)b * 65664 + (size_t)mm * 513 + tt] = e;
        lsum += e;
      }
    }
  }
  #pragma unroll
  for (int off = 32; off; off >>= 1) lsum += __shfl_xor(lsum, off);
  if ((tid & 63) == 0) red[tid >> 6] = lsum;
  __syncthreads();
  if (tid == 0)
    partials[b * 18 + blockIdx.x * 2 + blockIdx.y] =
        (red[0] + red[1]) + (red[2] + red[3]);
}

__global__ void sm_inv(const float* __restrict__ partials, float* __restrict__ invb)
{
  const int b = threadIdx.x;
  if (b < 64) {
    float s = 0.f;
    #pragma unroll
    for (int i = 0; i < 18; ++i) s += partials[b * 18 + i];
    invb[b] = 1.f / s;
  }
}

__global__ __launch_bounds__(256) void sm_norm(float* __restrict__ out,
                                               const float* __restrict__ invb)
{
  const int i4 = blockIdx.x * 256 + threadIdx.x;
  if (i4 < 1050624) {
    const int b = i4 / 16416;
    float4 v = ((float4*)out)[i4];
    const float s = invb[b];
    v.x *= s; v.y *= s; v.z *= s; v.w *= s;
    ((float4*)out)[i4] = v;
  }
}

// ---------------------------------------------------------------------------
extern "C" void kernel_launch(void* const* d_in, const int* in_sizes, int n_in,
                              void* d_out, int out_size, void* d_ws, size_t ws_size,
                              hipStream_t stream)
{
  const float* machine = (const float*)d_in[0];
  const float* jobs    = (const float*)d_in[1];
  const float* mask    = (const float*)d_in[2];
  const float* Wq      = (const float*)d_in[3];
  const float* Wk      = (const float*)d_in[4];
  const float* Wv      = (const float*)d_in[5];
  const float* Wc      = (const float*)d_in[6];
  const float* bc      = (const float*)d_in[7];
  const float* skip    = (const float*)d_in[8];

  // Workspace (floats). Peak 23,101,440 f = 92.4 MB (same as r1/r3/r4).
  float* ws       = (float*)d_ws;
  float* Qw       = ws;
  float* Kw       = ws + 2097152;
  float* Vw       = ws + 10502144;
  unsigned short* Wth = (unsigned short*)(ws + 18907136);  // dead before Opart written
  unsigned short* Wtl = Wth + 131072;
  float* Opart    = ws + 18907136;
  float* MH       = ws + 18907136;     // overlays Opart chunk0 (dead by then)
  float* partials = ws + 2097152;      // overlays Kw (dead after attn_part)
  float* invb     = partials + 1152;
  float* OC       = Qw;
  float* out      = (float*)d_out;
  float* Lpart    = out;               // dead before logits writes

  // Q = machine @ Wq3 (fp32)
  gemm_wide<0><<<dim3(2, 128), 256, 0, stream>>>(
      machine, nullptr, nullptr, Wq, nullptr, Qw);
  // W split/transpose, then K|V = vjobs @ [Wk|Wv] via split-bf16 MFMA
  prep_wt<<<512, 256, 0, stream>>>(Wk, Wv, Wth, Wtl);
  gemm_kv_mfma<<<dim3(4, 257), 256, 0, stream>>>(jobs, skip, Wth, Wtl, Kw, Vw);
  // attention partials (1 wave per (h,b,c), 2 m per lane) + combine
  attn_part<<<dim3(16, 64, 2), 64, 0, stream>>>(Qw, Kw, Vw, Opart, Lpart);
  attn_combine<<<512, 256, 0, stream>>>(Opart, Lpart, OC);
  // mh = out_concat @ Wc + bc (fp32)
  gemm_wide<0><<<dim3(2, 128), 256, 0, stream>>>(
      OC, nullptr, nullptr, Wc, bc, MH);
  // exp(logits-10) + partials
  logits_gemm<<<dim3(9, 2, 64), 256, 0, stream>>>(MH, jobs, skip, mask, out, partials);
  sm_inv<<<1, 64, 0, stream>>>(partials, invb);
  sm_norm<<<4104, 256, 0, stream>>>(out, invb);
}